// Round 7
// baseline (53.742 us; speedup 1.0000x reference)
//
#include <hip/hip_runtime.h>

// LIF forward scan, B=65536 rows x L=400 steps.
// Outputs (concatenated float32 in d_out):
//   [0,              B*L)    spikes (exactly 0.0/1.0)
//   [B*L,        B*L + B)    hard_latency (first spike index, or L) as float
//   [B*L + B,  B*L + 2*B)    soft_latency = sum(s*t) / (sum(s) + 1e-6)
//
// R5/R6: spikes kept as REGISTER BITS during the scan (no per-step LDS write).
// Per 160-step group: dump 5 u32/thread to LDS, then dense bit->float4
// expansion with fully sector-aligned nontemporal stores (640B/row segments).
// DS traffic drops 800 -> ~106 inst/wave; partial-sector writes eliminated.
// (R6 fix: nontemporal builtin needs a native ext_vector type, not HIP float4.)

constexpr int Bsz  = 65536;
constexpr int Lsz  = 400;
constexpr int ROWS = 64;            // ONE wave per block — barrier-free LDS
constexpr int TC   = 40;            // timesteps per chunk
constexpr int V4   = TC / 4;        // 10 float4 per chunk per thread

typedef float floatx4 __attribute__((ext_vector_type(4)));

// Expand one group's bits (CNT4 float4s per row) from LDS to global.
// Stores: consecutive lanes -> consecutive 16B -> 64B-sector-aligned dense runs.
template<int CNT4>
__device__ __forceinline__ void expand(const unsigned int* bits_lds, float* Sb,
                                       int tid, int t0f)
{
#pragma unroll
    for (int it = 0; it < CNT4; ++it) {
        const int idx = it * ROWS + tid;
        const int r   = idx / CNT4;          // magic-mul, no real div
        const int c4  = idx % CNT4;
        const unsigned int word = bits_lds[r * 8 + (c4 >> 3)];
        const int bb = (c4 & 7) * 4;
        floatx4 vv;
        vv.x = ((word >> (bb + 0)) & 1u) ? 1.0f : 0.0f;
        vv.y = ((word >> (bb + 1)) & 1u) ? 1.0f : 0.0f;
        vv.z = ((word >> (bb + 2)) & 1u) ? 1.0f : 0.0f;
        vv.w = ((word >> (bb + 3)) & 1u) ? 1.0f : 0.0f;
        __builtin_nontemporal_store(vv,
            reinterpret_cast<floatx4*>(Sb + (size_t)r * Lsz + t0f + c4 * 4));
    }
}

__global__ __launch_bounds__(ROWS)
void lif_kernel(const float* __restrict__ I, float* __restrict__ out)
{
    __shared__ unsigned int bits_lds[ROWS * 8];   // 2 KiB

    const int tid = threadIdx.x;
    const int rb  = blockIdx.x * ROWS;
    const int row = rb + tid;

    const float* Irow = I   + (size_t)row * Lsz;  // this thread's own row
    float*       Sb   = out + (size_t)rb  * Lsz;

    float4 regA[V4], regB[V4];

    auto glb_load = [&](int ch, float4* rg) {
#pragma unroll
        for (int it = 0; it < V4; ++it)
            rg[it] = *reinterpret_cast<const float4*>(Irow + ch * TC + it * 4);
    };

    float v     = 0.0f;
    float theta = 1.0f;
    int   allow = 0;                 // earliest step index that may spike
    int   first = Lsz;
    float cnt   = 0.0f;
    float swt   = 0.0f;
    unsigned int bw[5];              // group-local spike bits (static indices only)

    // one chunk of the scan; gb = bit offset within current group (LITERAL at
    // every call site -> bw indices fold to compile-time constants)
    auto body = [&](const float4* rg, int t0, int gb) {
        const float* in = reinterpret_cast<const float*>(rg);
        float cnt_l = 0.0f, swt_l = 0.0f;
#pragma unroll
        for (int c = 0; c < TC; ++c) {
            const float It = in[c];
            v = __builtin_fmaf(v, 0.95f, It);     // v += -v/20 + I
            const int t = t0 + c;
            const bool hard = (v >= theta) & (t >= allow);
            v     = hard ? 0.0f : v;
            theta = __builtin_fmaf(theta, 0.98f, hard ? 0.52f : 0.02f);
            allow = hard ? (t + 6) : allow;       // 5 blocked steps
            const int cg = gb + c;                // compile-time constant
            bw[cg >> 5] |= (hard ? (1u << (cg & 31)) : 0u);
            const float s = hard ? 1.0f : 0.0f;
            cnt_l += s;
            swt_l = __builtin_fmaf(s, (float)c, swt_l);
            first = hard ? min(first, t) : first;
        }
        swt = __builtin_fmaf(cnt_l, (float)t0, swt + swt_l);
        cnt += cnt_l;
    };

    auto dump_bits = [&]() {
        *reinterpret_cast<uint4*>(&bits_lds[tid * 8]) =
            make_uint4(bw[0], bw[1], bw[2], bw[3]);
        bits_lds[tid * 8 + 4] = bw[4];
    };

    glb_load(0, regA);
    glb_load(1, regB);

    // groups 0,1: chunks {0..3}, {4..7}; 160 steps = 5 bit-words = 640B/row
    for (int g = 0; g < 2; ++g) {
        bw[0] = bw[1] = bw[2] = bw[3] = bw[4] = 0u;
#pragma unroll
        for (int k = 0; k < 4; ++k) {
            const int ch = g * 4 + k;
            if ((k & 1) == 0) { body(regA, ch * TC, k * TC); glb_load(ch + 2, regA); }
            else              { body(regB, ch * TC, k * TC); glb_load(ch + 2, regB); }
        }
        dump_bits();
        expand<40>(bits_lds, Sb, tid, g * 160);   // no barrier: single-wave, DS in-order
    }

    // group 2: chunks 8,9; 80 steps = 320B/row (5 sectors, aligned)
    bw[0] = bw[1] = bw[2] = bw[3] = bw[4] = 0u;
    body(regA, 8 * TC, 0);
    body(regB, 9 * TC, 40);
    dump_bits();
    expand<20>(bits_lds, Sb, tid, 320);

    out[(size_t)Bsz * Lsz + row]       = (float)first;
    out[(size_t)Bsz * Lsz + Bsz + row] = swt / (cnt + 1e-6f);
}

extern "C" void kernel_launch(void* const* d_in, const int* in_sizes, int n_in,
                              void* d_out, int out_size, void* d_ws, size_t ws_size,
                              hipStream_t stream)
{
    const float* I = (const float*)d_in[0];
    float* out = (float*)d_out;
    lif_kernel<<<dim3(Bsz / ROWS), dim3(ROWS), 0, stream>>>(I, out);
}

// Round 8
// 48.098 us; speedup vs baseline: 1.1173x; 1.1173x over previous
//
#include <hip/hip_runtime.h>

// LIF forward scan, B=65536 rows x L=400 steps.
// Outputs (concatenated float32 in d_out):
//   [0,              B*L)    spikes (exactly 0.0/1.0)
//   [B*L,        B*L + B)    hard_latency (first spike index, or L) as float
//   [B*L + B,  B*L + 2*B)    soft_latency = sum(s*t) / (sum(s) + 1e-6)
//
// R7 = R4's proven pipeline (2-deep per-row register prefetch, 124 VGPR)
// + per-PAIR (80-step) spike bit-packing. Body writes no LDS; after each
// chunk pair: 1 ds_write_b128/thread + 20 ds_read_b32 in the expander,
// dense 320B/row float4 stores (5 aligned 64B sectors). DS ops 800->~115.
// R6's regression was the 160-step unrolled region hitting the 256-VGPR cap.

constexpr int Bsz  = 65536;
constexpr int Lsz  = 400;
constexpr int ROWS = 64;            // ONE wave per block — barrier-free LDS
constexpr int TC   = 40;            // timesteps per chunk
constexpr int NCH  = Lsz / TC;      // 10 chunks (loop steps by 2)
constexpr int V4   = TC / 4;        // 10 float4 per chunk per thread

__global__ __launch_bounds__(ROWS)
void lif_kernel(const float* __restrict__ I, float* __restrict__ out)
{
    __shared__ unsigned int bits_lds[ROWS * 4];   // 1 KiB (3 words + pad per row)

    const int tid = threadIdx.x;
    const int rb  = blockIdx.x * ROWS;
    const int row = rb + tid;

    const float* Irow = I   + (size_t)row * Lsz;  // this thread's own row
    float*       Sb   = out + (size_t)rb  * Lsz;

    float4 regA[V4], regB[V4];

    auto glb_load = [&](int ch, float4* rg) {
#pragma unroll
        for (int it = 0; it < V4; ++it)
            rg[it] = *reinterpret_cast<const float4*>(Irow + ch * TC + it * 4);
    };

    float v     = 0.0f;
    float theta = 1.0f;
    int   allow = 0;                 // earliest step index that may spike
    int   first = Lsz;
    float cnt   = 0.0f;
    float swt   = 0.0f;
    unsigned int bw0, bw1, bw2;      // pair-local spike bits (scalars: no array)

    // one chunk; gb = bit offset within pair (LITERAL 0 or 40 at call sites)
    auto body = [&](const float4* rg, int t0, int gb) {
        const float* in = reinterpret_cast<const float*>(rg);
        float cnt_l = 0.0f, swt_l = 0.0f;
#pragma unroll
        for (int c = 0; c < TC; ++c) {
            const float It = in[c];
            v = __builtin_fmaf(v, 0.95f, It);     // v += -v/20 + I
            const int t = t0 + c;
            const bool hard = (v >= theta) & (t >= allow);
            v     = hard ? 0.0f : v;
            theta = __builtin_fmaf(theta, 0.98f, hard ? 0.52f : 0.02f);
            allow = hard ? (t + 6) : allow;       // 5 blocked steps
            const int cg = gb + c;                // compile-time constant
            const unsigned int m = hard ? (1u << (cg & 31)) : 0u;
            if ((cg >> 5) == 0) bw0 |= m;
            else if ((cg >> 5) == 1) bw1 |= m;
            else bw2 |= m;
            const float s = hard ? 1.0f : 0.0f;
            cnt_l += s;
            swt_l = __builtin_fmaf(s, (float)c, swt_l);
            first = hard ? min(first, t) : first;
        }
        swt = __builtin_fmaf(cnt_l, (float)t0, swt + swt_l);
        cnt += cnt_l;
    };

    // expand one pair (80 steps = 20 float4 per row) from bits to global
    auto expand = [&](int pair) {
        *reinterpret_cast<uint4*>(&bits_lds[tid * 4]) = make_uint4(bw0, bw1, bw2, 0u);
        // single wave: DS ops execute in order, no barrier needed
#pragma unroll
        for (int it = 0; it < 20; ++it) {
            const int idx = it * ROWS + tid;
            const int r   = idx / 20;
            const int c4  = idx % 20;
            const unsigned int word = bits_lds[r * 4 + (c4 >> 3)];
            const int bb = (c4 & 7) * 4;
            float4 vv;
            vv.x = ((word >> (bb + 0)) & 1u) ? 1.0f : 0.0f;
            vv.y = ((word >> (bb + 1)) & 1u) ? 1.0f : 0.0f;
            vv.z = ((word >> (bb + 2)) & 1u) ? 1.0f : 0.0f;
            vv.w = ((word >> (bb + 3)) & 1u) ? 1.0f : 0.0f;
            *reinterpret_cast<float4*>(Sb + (size_t)r * Lsz + pair * 80 + c4 * 4) = vv;
        }
    };

    glb_load(0, regA);
    glb_load(1, regB);

    for (int ch = 0; ch < NCH; ch += 2) {
        bw0 = bw1 = bw2 = 0u;
        body(regA, ch * TC, 0);
        if (ch + 2 < NCH) glb_load(ch + 2, regA);
        body(regB, (ch + 1) * TC, 40);
        if (ch + 3 < NCH) glb_load(ch + 3, regB);
        expand(ch >> 1);
    }

    out[(size_t)Bsz * Lsz + row]       = (float)first;
    out[(size_t)Bsz * Lsz + Bsz + row] = swt / (cnt + 1e-6f);
}

extern "C" void kernel_launch(void* const* d_in, const int* in_sizes, int n_in,
                              void* d_out, int out_size, void* d_ws, size_t ws_size,
                              hipStream_t stream)
{
    const float* I = (const float*)d_in[0];
    float* out = (float*)d_out;
    lif_kernel<<<dim3(Bsz / ROWS), dim3(ROWS), 0, stream>>>(I, out);
}

// Round 9
// 46.762 us; speedup vs baseline: 1.1493x; 1.0286x over previous
//
#include <hip/hip_runtime.h>

// LIF forward scan, B=65536 rows x L=400 steps.
// Outputs (concatenated float32 in d_out):
//   [0,              B*L)    spikes (exactly 0.0/1.0)
//   [B*L,        B*L + B)    hard_latency (first spike index, or L) as float
//   [B*L + B,  B*L + 2*B)    soft_latency = sum(s*t) / (sum(s) + 1e-6)
//
// R8 = R4 (best, 41.9us) with ONE change: input gather -> coalesced
// global_load_lds staging. R4's per-thread-row loads put 64 lanes on 64
// distinct cache lines per instruction (~64 addr-pipe transactions); the
// LDS-DMA path stages the 64x40 chunk with ~17 lines/inst, and each thread
// reads its own row back via 10x ds_read_b128. Body + output path unchanged.

constexpr int Bsz  = 65536;
constexpr int Lsz  = 400;
constexpr int ROWS = 64;            // ONE wave per block — barrier-free LDS
constexpr int TC   = 40;            // timesteps per chunk
constexpr int NCH  = Lsz / TC;      // 10
constexpr int STRIDE = TC + 1;      // 41: (9*tid + c) % 32 -> 2 lanes/bank, free
constexpr int V4   = TC / 4;        // 10 float4 per chunk per thread

__device__ __forceinline__ void gl2lds16(const float* g, float* l)
{
    // stages 16B per lane: LDS dest = l + lane*16 (wave-uniform base),
    // global src = per-lane pointer g. size must be a literal.
    __builtin_amdgcn_global_load_lds(
        (const __attribute__((address_space(1))) void*)g,
        (__attribute__((address_space(3))) void*)l,
        16, 0, 0);
}

__global__ __launch_bounds__(ROWS)
void lif_kernel(const float* __restrict__ I, float* __restrict__ out)
{
    __shared__ float inbuf[2][ROWS * TC];   // 2 x 10,240 B, linear [row][40]
    __shared__ float tile[ROWS * STRIDE];   // 10,496 B (output transpose)

    const int tid = threadIdx.x;
    const int rb  = blockIdx.x * ROWS;
    const int row = rb + tid;

    const float* Ib = I   + (size_t)rb * Lsz;
    float*       Sb = out + (size_t)rb * Lsz;

    // Instruction k stages LDS float range [k*256, k*256+256) (lane l -> 16B
    // at float offset k*256 + l*4 = 4*idx, idx = k*64+l). Matching global
    // source: r = idx/10, c4 = idx%10 -> element (rb+r)*Lsz + ch*40 + c4*4.
    // Consecutive lanes advance c4 within a row -> coalesced (~17 lines/inst).
    int goff[V4];
#pragma unroll
    for (int k = 0; k < V4; ++k) {
        const int idx = k * ROWS + tid;
        const int r   = idx / V4;
        const int c4  = idx % V4;
        goff[k] = r * Lsz + c4 * 4;
    }

    auto issue = [&](int ch, float* buf) {
#pragma unroll
        for (int k = 0; k < V4; ++k)
            gl2lds16(Ib + goff[k] + ch * TC, buf + k * 256);
    };

    float v     = 0.0f;
    float theta = 1.0f;
    int   allow = 0;                 // earliest step index that may spike
    int   first = Lsz;
    float cnt   = 0.0f;
    float swt   = 0.0f;
    float4 rg[V4];

    auto body = [&](int ch) {
        float* myrow = &tile[tid * STRIDE];
        const float* in = reinterpret_cast<const float*>(rg);
        float cnt_l = 0.0f, swt_l = 0.0f;
        const int t0 = ch * TC;
#pragma unroll
        for (int c = 0; c < TC; ++c) {
            const float It = in[c];
            v = __builtin_fmaf(v, 0.95f, It);     // v += -v/20 + I
            const int t = t0 + c;
            const bool hard = (v >= theta) & (t >= allow);
            const float s   = hard ? 1.0f : 0.0f;
            v     = hard ? 0.0f : v;
            theta = __builtin_fmaf(theta, 0.98f, hard ? 0.52f : 0.02f);
            allow = hard ? (t + 6) : allow;       // 5 blocked steps
            myrow[c] = s;
            cnt_l += s;
            swt_l = __builtin_fmaf(s, (float)c, swt_l);
            first = hard ? min(first, t) : first;
        }
        swt = __builtin_fmaf(cnt_l, (float)t0, swt + swt_l);
        cnt += cnt_l;
    };

    auto store = [&](int ch) {
        const int t0 = ch * TC;
#pragma unroll
        for (int it = 0; it < V4; ++it) {
            const int idx = it * ROWS + tid;
            const int r   = idx / V4;
            const int c4  = idx % V4;
            const float* sp = &tile[r * STRIDE + c4 * 4];
            const float4 vv = make_float4(sp[0], sp[1], sp[2], sp[3]);
            *reinterpret_cast<float4*>(Sb + r * Lsz + t0 + c4 * 4) = vv;
        }
    };

    issue(0, inbuf[0]);
    issue(1, inbuf[1]);

    for (int ch = 0; ch < NCH; ++ch) {
        float* buf = inbuf[ch & 1];
        // own row LDS -> regs (compiler inserts the LDS-DMA vmcnt wait here)
#pragma unroll
        for (int j = 0; j < V4; ++j)
            rg[j] = *reinterpret_cast<const float4*>(&buf[tid * TC + j * 4]);
        body(ch);
        // reuse buf for ch+2 only after rg is fully read (body consumed it);
        // loads get body(ch+1)+2 stores (~1500+ cyc) of cover before their wait
        if (ch + 2 < NCH) issue(ch + 2, buf);
        store(ch);
    }

    out[(size_t)Bsz * Lsz + row]       = (float)first;
    out[(size_t)Bsz * Lsz + Bsz + row] = swt / (cnt + 1e-6f);
}

extern "C" void kernel_launch(void* const* d_in, const int* in_sizes, int n_in,
                              void* d_out, int out_size, void* d_ws, size_t ws_size,
                              hipStream_t stream)
{
    const float* I = (const float*)d_in[0];
    float* out = (float*)d_out;
    lif_kernel<<<dim3(Bsz / ROWS), dim3(ROWS), 0, stream>>>(I, out);
}

// Round 10
// 38.000 us; speedup vs baseline: 1.4142x; 1.2306x over previous
//
#include <hip/hip_runtime.h>

// LIF forward scan, B=65536 rows x L=400 steps.
// Outputs (concatenated float32 in d_out):
//   [0,              B*L)    spikes (exactly 0.0/1.0)
//   [B*L,        B*L + B)    hard_latency (first spike index, or L) as float
//   [B*L + B,  B*L + 2*B)    soft_latency = sum(s*t) / (sum(s) + 1e-6)
//
// R9 = R4 (best, 41.9us) with the store path made dense + nontemporal:
// transpose tile holds TWO chunks ([64][81], 20.7KB), stores are 320B/row
// runs = exactly 5 aligned 64B sectors (kills the 160B-run half-sector leak,
// ~-12MB WRITE), nontemporal (spikes are write-once; keeps L3 for the input,
// ~-8MB FETCH). Same instruction counts as R4 -> VALU/VGPR-neutral.

constexpr int Bsz  = 65536;
constexpr int Lsz  = 400;
constexpr int ROWS = 64;            // ONE wave per block — barrier-free LDS
constexpr int TC   = 40;            // timesteps per chunk
constexpr int NCH  = Lsz / TC;      // 10 chunks (loop steps by 2)
constexpr int PW   = 2 * TC;        // 80 steps buffered per store pass
constexpr int STRIDE = PW + 1;      // 81: write bank = (17*tid+c)%32 -> 2/bank, free
constexpr int V4   = TC / 4;        // 10 float4 per chunk per thread
constexpr int PV4  = PW / 4;        // 20 float4 per pair per row

typedef float floatx4 __attribute__((ext_vector_type(4)));

__global__ __launch_bounds__(ROWS)
void lif_kernel(const float* __restrict__ I, float* __restrict__ out)
{
    __shared__ float tile[ROWS * STRIDE];   // 20,736 B (output transpose, 2 chunks)

    const int tid = threadIdx.x;
    const int rb  = blockIdx.x * ROWS;
    const int row = rb + tid;

    const float* Irow = I   + (size_t)row * Lsz;   // this thread's own row
    float*       Sb   = out + (size_t)rb  * Lsz;

    float4 regA[V4], regB[V4];

    auto glb_load = [&](int ch, float4* rg) {
#pragma unroll
        for (int it = 0; it < V4; ++it)
            rg[it] = *reinterpret_cast<const float4*>(Irow + ch * TC + it * 4);
    };

    float v     = 0.0f;
    float theta = 1.0f;
    int   allow = 0;                // earliest step index that may spike
    int   first = Lsz;
    float cnt   = 0.0f;
    float swt   = 0.0f;

    // one chunk; off = column offset in tile (LITERAL 0 or 40 at call sites)
    auto body = [&](const float4* rg, int t0, int off) {
        float* myrow = &tile[tid * STRIDE + off];
        const float* in = reinterpret_cast<const float*>(rg);
        float cnt_l = 0.0f, swt_l = 0.0f;
#pragma unroll
        for (int c = 0; c < TC; ++c) {
            const float It = in[c];
            v = __builtin_fmaf(v, 0.95f, It);     // v += -v/20 + I
            const int t = t0 + c;
            const bool hard = (v >= theta) & (t >= allow);
            const float s   = hard ? 1.0f : 0.0f;
            v     = hard ? 0.0f : v;
            theta = __builtin_fmaf(theta, 0.98f, hard ? 0.52f : 0.02f);
            allow = hard ? (t + 6) : allow;       // 5 blocked steps
            myrow[c] = s;
            cnt_l += s;
            swt_l = __builtin_fmaf(s, (float)c, swt_l);
            first = hard ? min(first, t) : first;
        }
        swt = __builtin_fmaf(cnt_l, (float)t0, swt + swt_l);
        cnt += cnt_l;
    };

    // store one pair (80 steps): 320B/row dense runs, nontemporal
    auto store_pair = [&](int pair) {
#pragma unroll
        for (int it = 0; it < PV4; ++it) {
            const int idx = it * ROWS + tid;
            const int r   = idx / PV4;
            const int c4  = idx % PV4;
            const float* sp = &tile[r * STRIDE + c4 * 4];
            floatx4 vv = { sp[0], sp[1], sp[2], sp[3] };
            __builtin_nontemporal_store(vv,
                reinterpret_cast<floatx4*>(Sb + (size_t)r * Lsz + pair * PW + c4 * 4));
        }
    };

    glb_load(0, regA);
    glb_load(1, regB);

    for (int ch = 0; ch < NCH; ch += 2) {
        body(regA, ch * TC, 0);
        if (ch + 2 < NCH) glb_load(ch + 2, regA);
        body(regB, (ch + 1) * TC, TC);
        if (ch + 3 < NCH) glb_load(ch + 3, regB);
        store_pair(ch >> 1);        // single wave: DS in order, no barrier
    }

    out[(size_t)Bsz * Lsz + row]       = (float)first;
    out[(size_t)Bsz * Lsz + Bsz + row] = swt / (cnt + 1e-6f);
}

extern "C" void kernel_launch(void* const* d_in, const int* in_sizes, int n_in,
                              void* d_out, int out_size, void* d_ws, size_t ws_size,
                              hipStream_t stream)
{
    const float* I = (const float*)d_in[0];
    float* out = (float*)d_out;
    lif_kernel<<<dim3(Bsz / ROWS), dim3(ROWS), 0, stream>>>(I, out);
}

// Round 11
// 37.739 us; speedup vs baseline: 1.4240x; 1.0069x over previous
//
#include <hip/hip_runtime.h>

// LIF forward scan, B=65536 rows x L=400 steps.
// Outputs (concatenated float32 in d_out):
//   [0,              B*L)    spikes (exactly 0.0/1.0)
//   [B*L,        B*L + B)    hard_latency (first spike index, or L) as float
//   [B*L + B,  B*L + 2*B)    soft_latency = sum(s*t) / (sum(s) + 1e-6)
//
// R10: producer-consumer wave specialization. Block = 128 threads = 2 waves:
//   wave0 (compute): LDS->reg input, 400-step scan, spikes as BITS -> LDS,
//                    cnt/swt/first via popcount/ffs per 80-step pair (exact).
//   wave1 (memory):  per-row global gather -> LDS input staging (1 phase
//                    lookahead), bit->float4 expand + nontemporal stores.
// 2 waves/SIMD (vs 1), memory waits moved off the scan's critical path.
// 2 barriers per pair; loads issued early each phase so the pre-barrier
// vmcnt(0) drain overlaps the concurrent compute (~1.3k cyc > HBM latency).

constexpr int Bsz  = 65536;
constexpr int Lsz  = 400;
constexpr int ROWS = 64;            // rows per block (one per compute lane)
constexpr int TC   = 40;            // timesteps per chunk (phase)
constexpr int STRIDE = 41;          // in2 row stride: (9*lane+c)%32 -> 2/bank, free
constexpr int V4   = TC / 4;        // 10 float4 per chunk per row

typedef float floatx4 __attribute__((ext_vector_type(4)));

__device__ __forceinline__ int sumpos(unsigned int w) {
    // sum of set-bit positions within a 32-bit word (exact, ~13 VALU)
    return __popc(w & 0xAAAAAAAAu) + (__popc(w & 0xCCCCCCCCu) << 1) +
           (__popc(w & 0xF0F0F0F0u) << 2) + (__popc(w & 0xFF00FF00u) << 3) +
           (__popc(w & 0xFFFF0000u) << 4);
}

__global__ __launch_bounds__(2 * ROWS)
void lif_kernel(const float* __restrict__ I, float* __restrict__ out)
{
    __shared__ float in2[2][ROWS * STRIDE];        // 2 x 10,496 B input staging
    __shared__ unsigned int bits[2][ROWS * 4];     // 2 x 1 KiB spike bits

    const int tid  = threadIdx.x;
    const int wv   = tid >> 6;       // 0 = compute wave, 1 = memory wave
    const int lane = tid & 63;
    const int rb   = blockIdx.x * ROWS;

    if (wv == 1) {
        // ------------------------- memory wave -------------------------
        const float* Irow = I + (size_t)(rb + lane) * Lsz;   // own row
        float* Sb = out + (size_t)rb * Lsz;
        float4 rg[V4];

        auto issue = [&](int ch) {
#pragma unroll
            for (int it = 0; it < V4; ++it)
                rg[it] = *reinterpret_cast<const float4*>(Irow + ch * TC + it * 4);
        };
        auto put = [&](int buf) {    // regs -> in2[buf], row-major stride 41
            const float* f = reinterpret_cast<const float*>(rg);
            float* dst = &in2[buf][lane * STRIDE];
#pragma unroll
            for (int c = 0; c < TC; ++c) dst[c] = f[c];
        };
        auto expand_half = [&](int pair, int half) {   // 10 of 20 float4/row
            const unsigned int* bl = bits[pair & 1];
#pragma unroll
            for (int q = 0; q < 10; ++q) {
                const int it  = half * 10 + q;
                const int idx = it * ROWS + lane;
                const int r   = idx / 20;
                const int c4  = idx % 20;
                const unsigned int word = bl[r * 4 + (c4 >> 3)];
                const int bb = (c4 & 7) * 4;
                floatx4 vv = { (float)((word >> (bb + 0)) & 1u),
                               (float)((word >> (bb + 1)) & 1u),
                               (float)((word >> (bb + 2)) & 1u),
                               (float)((word >> (bb + 3)) & 1u) };
                __builtin_nontemporal_store(vv,
                    reinterpret_cast<floatx4*>(Sb + (size_t)r * Lsz + pair * 80 + c4 * 4));
            }
        };

        issue(0); put(0); issue(1);          // ch0 staged; ch1 in flight
        __syncthreads();
        for (int pr = 0; pr < 5; ++pr) {
            const int ch = 2 * pr;
            // phase A (compute scans ch): stage ch+1, issue ch+2, expand prev pair
            put(1);
            if (ch + 2 < 10) issue(ch + 2);
            if (pr >= 1) expand_half(pr - 1, 0);
            __syncthreads();
            // phase B (compute scans ch+1): stage ch+2, issue ch+3, expand rest
            if (ch + 2 < 10) put(0);
            if (ch + 3 < 10) issue(ch + 3);
            if (pr >= 1) expand_half(pr - 1, 1);
            __syncthreads();
        }
        expand_half(4, 0); expand_half(4, 1);          // last pair
    } else {
        // ------------------------- compute wave ------------------------
        float v = 0.0f, theta = 1.0f;
        int allow = 0, first = Lsz;
        int cnt_i = 0, swt_i = 0;            // integer-exact reductions
        unsigned int w0, w1, w2;

        // scan one 40-step chunk; gb = bit offset within pair (LITERAL 0/40)
        auto scan_chunk = [&](int buf, int t0, int gb) {
            const float* src = &in2[buf][lane * STRIDE];
            float rg[TC];
#pragma unroll
            for (int c = 0; c < TC; ++c) rg[c] = src[c];   // batch LDS->reg
#pragma unroll
            for (int c = 0; c < TC; ++c) {
                v = __builtin_fmaf(v, 0.95f, rg[c]);       // v += -v/20 + I
                const int t = t0 + c;
                const bool hard = (v >= theta) & (t >= allow);
                v     = hard ? 0.0f : v;
                theta = __builtin_fmaf(theta, 0.98f, hard ? 0.52f : 0.02f);
                allow = hard ? (t + 6) : allow;            // 5 blocked steps
                const int cg = gb + c;                     // compile-time
                const unsigned int m = hard ? (1u << (cg & 31)) : 0u;
                if (cg < 32) w0 |= m; else if (cg < 64) w1 |= m; else w2 |= m;
            }
        };

        __syncthreads();                      // matches memory prologue barrier
        for (int pr = 0; pr < 5; ++pr) {
            w0 = w1 = w2 = 0u;
            scan_chunk(0, 2 * pr * TC, 0);
            __syncthreads();
            scan_chunk(1, (2 * pr + 1) * TC, TC);
            // pair-end reductions (exact) + publish bits for the memory wave
            const int tp = pr * 80;
            const int p0 = __popc(w0), p1 = __popc(w1), p2 = __popc(w2);
            const int cp = p0 + p1 + p2;
            cnt_i += cp;
            swt_i += tp * cp + sumpos(w0) + sumpos(w1) + 32 * p1 +
                     sumpos(w2) + 64 * p2;
            const int cand = w0 ? tp + (__ffs(w0) - 1)
                           : w1 ? tp + 32 + (__ffs(w1) - 1)
                           : w2 ? tp + 64 + (__ffs(w2) - 1) : Lsz;
            first = min(first, cand);
            *reinterpret_cast<uint4*>(&bits[pr & 1][lane * 4]) =
                make_uint4(w0, w1, w2, 0u);
            __syncthreads();
        }
        const int row = rb + lane;
        out[(size_t)Bsz * Lsz + row]       = (float)first;
        out[(size_t)Bsz * Lsz + Bsz + row] = (float)swt_i / ((float)cnt_i + 1e-6f);
    }
}

extern "C" void kernel_launch(void* const* d_in, const int* in_sizes, int n_in,
                              void* d_out, int out_size, void* d_ws, size_t ws_size,
                              hipStream_t stream)
{
    const float* I = (const float*)d_in[0];
    float* out = (float*)d_out;
    lif_kernel<<<dim3(Bsz / ROWS), dim3(2 * ROWS), 0, stream>>>(I, out);
}